// Round 1
// baseline (2711.132 us; speedup 1.0000x reference)
//
#include <hip/hip_runtime.h>
#include <math.h>

#define TT 512
#define BB 128
#define OBSD 512
#define HD 256
#define PD 128
#define LD 4
#define AD 4
#define NTB (TT*BB)   // 65536

__device__ __forceinline__ float gelu_f(float x) {
    float x3 = x * x * x;
    return 0.5f * x * (1.f + tanhf(0.7978845608028654f * (x + 0.044715f * x3)));
}

// ---------------- GEMM: C[M,N] = A[M,K] @ B[K,N] (+epilogue) ----------------
// MODE 0: leaky_relu(acc + bias[n])
// MODE 1: acc
// MODE 3: acc + bias[n]*aux1[idx]   (ys = xsC + d*u; C may alias aux1)
// MODE 4: aux2[idx] += aux1[idx] * sigmoid(acc + bias[n])   (GLU + skip)
template<int MODE>
__global__ __launch_bounds__(256) void gemm_k(
    const float* __restrict__ A, const float* __restrict__ Bm, float* C,
    int M, int N, int K,
    const float* __restrict__ bias, const float* aux1, float* aux2)
{
    __shared__ float As[16][65];
    __shared__ float Bs[16][64];
    int tid = threadIdx.x;
    int tx = tid & 15, ty = tid >> 4;
    int m0 = blockIdx.x * 64, n0 = blockIdx.y * 64;
    float acc[4][4] = {};
    for (int k0 = 0; k0 < K; k0 += 16) {
#pragma unroll
        for (int it = 0; it < 4; ++it) {
            int m = (tid >> 4) + it * 16;
            int kk = tid & 15;
            As[kk][m] = A[(size_t)(m0 + m) * K + k0 + kk];
        }
#pragma unroll
        for (int it = 0; it < 4; ++it) {
            int kk = (tid >> 6) + it * 4;
            int n = tid & 63;
            Bs[kk][n] = Bm[(size_t)(k0 + kk) * N + n0 + n];
        }
        __syncthreads();
#pragma unroll
        for (int kk = 0; kk < 16; ++kk) {
            float a[4], b[4];
#pragma unroll
            for (int i = 0; i < 4; ++i) a[i] = As[kk][ty * 4 + i];
#pragma unroll
            for (int j = 0; j < 4; ++j) b[j] = Bs[kk][tx * 4 + j];
#pragma unroll
            for (int i = 0; i < 4; ++i)
#pragma unroll
                for (int j = 0; j < 4; ++j)
                    acc[i][j] += a[i] * b[j];
        }
        __syncthreads();
    }
#pragma unroll
    for (int i = 0; i < 4; ++i) {
        int m = m0 + ty * 4 + i;
#pragma unroll
        for (int j = 0; j < 4; ++j) {
            int n = n0 + tx * 4 + j;
            size_t idx = (size_t)m * N + n;
            float v = acc[i][j];
            if (MODE == 0) { v += bias[n]; C[idx] = v > 0.f ? v : 0.01f * v; }
            else if (MODE == 1) { C[idx] = v; }
            else if (MODE == 3) { C[idx] = v + bias[n] * aux1[idx]; }
            else if (MODE == 4) {
                float s = 1.f / (1.f + expf(-(v + bias[n])));
                aux2[idx] = aux2[idx] + aux1[idx] * s;
            }
        }
    }
}

// ---------------- LayerNorm (one wave per row of 256), optional gelu --------
template<int GELU>
__global__ __launch_bounds__(256) void ln_k(const float* in, float* out,
    const float* __restrict__ scale, const float* __restrict__ bias)
{
    int wid = threadIdx.x >> 6, lane = threadIdx.x & 63;
    int row = blockIdx.x * 4 + wid;
    float4 v = ((const float4*)(in + (size_t)row * 256))[lane];
    float s = v.x + v.y + v.z + v.w;
#pragma unroll
    for (int off = 32; off; off >>= 1) s += __shfl_xor(s, off);
    float mu = s * (1.f / 256.f);
    float dx = v.x - mu, dy = v.y - mu, dz = v.z - mu, dw = v.w - mu;
    float q = dx * dx + dy * dy + dz * dz + dw * dw;
#pragma unroll
    for (int off = 32; off; off >>= 1) q += __shfl_xor(q, off);
    float rstd = rsqrtf(q * (1.f / 256.f) + 1e-6f);
    float4 sc = ((const float4*)scale)[lane];
    float4 bi = ((const float4*)bias)[lane];
    float4 o;
    o.x = dx * rstd * sc.x + bi.x;
    o.y = dy * rstd * sc.y + bi.y;
    o.z = dz * rstd * sc.z + bi.z;
    o.w = dw * rstd * sc.w + bi.w;
    if (GELU) { o.x = gelu_f(o.x); o.y = gelu_f(o.y); o.z = gelu_f(o.z); o.w = gelu_f(o.w); }
    ((float4*)(out + (size_t)row * 256))[lane] = o;
}

// ---------------- Sequential scan over T, one thread per (b,p) chain --------
__global__ __launch_bounds__(256) void scan_k(float* bu,
    const float* __restrict__ dones,
    const float* __restrict__ h0re, const float* __restrict__ h0im,
    const float* __restrict__ lamre, const float* __restrict__ lamim,
    const float* __restrict__ lstep, float* outre, float* outim)
{
    int gid = blockIdx.x * 256 + threadIdx.x;
    int b = gid >> 7, p = gid & 127;
    float lr = lamre[p], li = lamim[p];
    float st = expf(lstep[p]);
    float er = expf(lr * st);
    float ar = er * cosf(li * st);
    float ai = er * sinf(li * st);
    float hr = h0re[gid], hi = h0im[gid];
    for (int t = 0; t < TT; ++t) {
        size_t base = ((size_t)t * BB + b) * 256;
        float c = dones[t * BB + b];
        float br = bu[base + p], bim = bu[base + 128 + p];
        float nr, ni;
        if (c != 0.f) { nr = br; ni = bim; }
        else { nr = ar * hr - ai * hi + br; ni = ar * hi + ai * hr + bim; }
        hr = nr; hi = ni;
        bu[base + p] = nr; bu[base + 128 + p] = ni;
    }
    outre[gid] = hr;
    outim[gid] = hi;
}

// ---------------- Precompute B_bar (H x 2P packed) and Ccat (2P x H) --------
__global__ __launch_bounds__(256) void prep_k(
    const float* __restrict__ Br, const float* __restrict__ Bi,
    const float* __restrict__ Cr, const float* __restrict__ Ci,
    const float* __restrict__ Lr, const float* __restrict__ Li,
    const float* __restrict__ ls, float* bbar, float* ccat)
{
    int gid = blockIdx.x * 256 + threadIdx.x;   // L*P*H = 131072
    int l = gid >> 15;
    int rem = gid & 32767;
    int p = rem >> 8;
    int h = rem & 255;
    float lr = Lr[l * PD + p], li = Li[l * PD + p];
    float st = expf(ls[l * PD + p]);
    float er = expf(lr * st);
    float lbr = er * cosf(li * st);
    float lbi = er * sinf(li * st);
    float nr = lbr - 1.f, ni = lbi;
    float den = lr * lr + li * li;
    float fr = (nr * lr + ni * li) / den;
    float fi = (ni * lr - nr * li) / den;
    float bre = Br[(size_t)(l * PD + p) * HD + h];
    float bim = Bi[(size_t)(l * PD + p) * HD + h];
    size_t lb = (size_t)l * 65536;
    bbar[lb + (size_t)h * 256 + p]        = fr * bre - fi * bim;
    bbar[lb + (size_t)h * 256 + 128 + p]  = fr * bim + fi * bre;
    float cre = Cr[(size_t)(l * HD + h) * PD + p];
    float cim = Ci[(size_t)(l * HD + h) * PD + p];
    ccat[lb + (size_t)p * 256 + h]         = 2.f * cre;
    ccat[lb + (size_t)(128 + p) * 256 + h] = -2.f * cim;
}

// ---------------- Final heads: wave per row -> out[row*9 + ...] -------------
__global__ __launch_bounds__(256) void head_k(
    const float* __restrict__ am2, const float* __restrict__ v2,
    const float* __restrict__ adW, const float* __restrict__ adb,
    const float* __restrict__ lstd,
    const float* __restrict__ vdW, const float* __restrict__ vdb,
    float* out)
{
    int wid = threadIdx.x >> 6, lane = threadIdx.x & 63;
    int row = blockIdx.x * 4 + wid;
    float a1 = am2[(size_t)row * 128 + lane];
    float a2 = am2[(size_t)row * 128 + 64 + lane];
    float w1 = v2[(size_t)row * 128 + lane];
    float w2 = v2[(size_t)row * 128 + 64 + lane];
    float vals[5];
#pragma unroll
    for (int a = 0; a < 4; ++a)
        vals[a] = a1 * adW[lane * 4 + a] + a2 * adW[(lane + 64) * 4 + a];
    vals[4] = w1 * vdW[lane] + w2 * vdW[64 + lane];
#pragma unroll
    for (int off = 32; off; off >>= 1)
#pragma unroll
        for (int k = 0; k < 5; ++k) vals[k] += __shfl_xor(vals[k], off);
    if (lane == 0) {
        size_t o = (size_t)row * 9;
#pragma unroll
        for (int a = 0; a < 4; ++a) out[o + a] = vals[a] + adb[a];
#pragma unroll
        for (int a = 0; a < 4; ++a) out[o + 4 + a] = expf(lstd[a]);
        out[o + 8] = vals[4] + vdb[0];
    }
}

extern "C" void kernel_launch(void* const* d_in, const int* in_sizes, int n_in,
                              void* d_out, int out_size, void* d_ws, size_t ws_size,
                              hipStream_t stream) {
    (void)in_sizes; (void)n_in; (void)out_size; (void)ws_size;
    const float* obs     = (const float*)d_in[0];
    const float* dones   = (const float*)d_in[1];
    const float* hre     = (const float*)d_in[2];
    const float* him     = (const float*)d_in[3];
    const float* enc0_W  = (const float*)d_in[4];
    const float* enc0_b  = (const float*)d_in[5];
    const float* enc1_W  = (const float*)d_in[6];
    const float* enc1_b  = (const float*)d_in[7];
    const float* nsc     = (const float*)d_in[8];
    const float* nbi     = (const float*)d_in[9];
    const float* Lre     = (const float*)d_in[10];
    const float* Lim     = (const float*)d_in[11];
    const float* B_re    = (const float*)d_in[12];
    const float* B_im    = (const float*)d_in[13];
    const float* C_re    = (const float*)d_in[14];
    const float* C_im    = (const float*)d_in[15];
    const float* Dv      = (const float*)d_in[16];
    const float* lstep   = (const float*)d_in[17];
    const float* glu_W   = (const float*)d_in[18];
    const float* glu_b   = (const float*)d_in[19];
    const float* ab0_W   = (const float*)d_in[20];
    const float* ab0_b   = (const float*)d_in[21];
    const float* ab1_W   = (const float*)d_in[22];
    const float* ab1_b   = (const float*)d_in[23];
    const float* adec_W  = (const float*)d_in[24];
    const float* adec_b  = (const float*)d_in[25];
    const float* log_std = (const float*)d_in[26];
    const float* vb0_W   = (const float*)d_in[27];
    const float* vb0_b   = (const float*)d_in[28];
    const float* vb1_W   = (const float*)d_in[29];
    const float* vb1_b   = (const float*)d_in[30];
    const float* vdec_W  = (const float*)d_in[31];
    const float* vdec_b  = (const float*)d_in[32];

    float* ws = (float*)d_ws;
    float* X    = ws;                    // 16777216 floats (T,B,256) residual
    float* U    = ws + 16777216;         // 16777216 floats (T,B,256) u / ys / z
    float* BU   = ws + 33554432;         // 16777216 floats (T,B,2P) Bu/xs packed
    float* BBAR = ws + 50331648;         // 4*65536
    float* CCAT = BBAR + 262144;         // 4*65536

    float* out   = (float*)d_out;
    float* outre = out + (size_t)NTB * 9;        // 589824
    float* outim = outre + LD * BB * PD;         // +65536

    prep_k<<<512, 256, 0, stream>>>(B_re, B_im, C_re, C_im, Lre, Lim, lstep, BBAR, CCAT);

    // encoder
    gemm_k<0><<<dim3(NTB / 64, 2), 256, 0, stream>>>(obs, enc0_W, U, NTB, 128, 512, enc0_b, nullptr, nullptr);
    gemm_k<0><<<dim3(NTB / 64, 4), 256, 0, stream>>>(U, enc1_W, X, NTB, 256, 128, enc1_b, nullptr, nullptr);

    for (int l = 0; l < LD; ++l) {
        const float* sc = nsc + l * HD;
        const float* bi = nbi + l * HD;
        ln_k<0><<<NTB / 4, 256, 0, stream>>>(X, U, sc, bi);
        gemm_k<1><<<dim3(NTB / 64, 4), 256, 0, stream>>>(U, BBAR + (size_t)l * 65536, BU, NTB, 256, 256, nullptr, nullptr, nullptr);
        scan_k<<<64, 256, 0, stream>>>(BU, dones, hre + l * BB * PD, him + l * BB * PD,
                                       Lre + l * PD, Lim + l * PD, lstep + l * PD,
                                       outre + l * BB * PD, outim + l * BB * PD);
        gemm_k<3><<<dim3(NTB / 64, 4), 256, 0, stream>>>(BU, CCAT + (size_t)l * 65536, U, NTB, 256, 256, Dv + l * HD, U, nullptr);
        ln_k<1><<<NTB / 4, 256, 0, stream>>>(U, U, sc, bi);
        gemm_k<4><<<dim3(NTB / 64, 4), 256, 0, stream>>>(U, glu_W + (size_t)l * HD * HD, X, NTB, 256, 256, glu_b + l * HD, U, X);
    }

    // heads
    float* AM1 = U;
    float* V1  = U + 8388608;
    float* AM2 = BU;
    float* V2  = BU + 8388608;
    gemm_k<0><<<dim3(NTB / 64, 2), 256, 0, stream>>>(X, ab0_W, AM1, NTB, 128, 256, ab0_b, nullptr, nullptr);
    gemm_k<0><<<dim3(NTB / 64, 2), 256, 0, stream>>>(AM1, ab1_W, AM2, NTB, 128, 128, ab1_b, nullptr, nullptr);
    gemm_k<0><<<dim3(NTB / 64, 2), 256, 0, stream>>>(X, vb0_W, V1, NTB, 128, 256, vb0_b, nullptr, nullptr);
    gemm_k<0><<<dim3(NTB / 64, 2), 256, 0, stream>>>(V1, vb1_W, V2, NTB, 128, 128, vb1_b, nullptr, nullptr);
    head_k<<<NTB / 4, 256, 0, stream>>>(AM2, V2, adec_W, adec_b, log_std, vdec_W, vdec_b, out);
}

// Round 2
// 1360.064 us; speedup vs baseline: 1.9934x; 1.9934x over previous
//
#include <hip/hip_runtime.h>
#include <math.h>

#define TT 512
#define BB 128
#define OBSD 512
#define HD 256
#define PD 128
#define LD 4
#define NTB (TT*BB)   // 65536

typedef __bf16 bf16x8 __attribute__((ext_vector_type(8)));
typedef float  f32x4  __attribute__((ext_vector_type(4)));

__device__ __forceinline__ float bf2f(unsigned short u) {
    return __uint_as_float(((unsigned)u) << 16);
}
__device__ __forceinline__ unsigned short f2bf(float f) {
    unsigned u = __float_as_uint(f);
    unsigned r = (u + 0x7FFFu + ((u >> 16) & 1u)) >> 16;
    return (unsigned short)r;
}
__device__ __forceinline__ float gelu_f(float x) {
    float x3 = x * x * x;
    return 0.5f * x * (1.f + tanhf(0.7978845608028654f * (x + 0.044715f * x3)));
}

// ---- stage a 128x32 bf16 tile (row-major, 64B rows) into LDS via global_load_lds ----
__device__ __forceinline__ void stage_tile(const unsigned short* gbase, int ldk,
                                           int row0, int k0, unsigned short* sm, int tid)
{
    int w = tid >> 6, lane = tid & 63;
#pragma unroll
    for (int p = 0; p < 2; ++p) {
        int r = p * 64 + w * 16 + (lane >> 2);
        const unsigned short* g = gbase + (size_t)(row0 + r) * ldk + k0 + (lane & 3) * 8;
        unsigned short* l = sm + (p * 64 + w * 16) * 32;
        __builtin_amdgcn_global_load_lds(
            (const __attribute__((address_space(1))) void*)g,
            (__attribute__((address_space(3))) void*)l, 16, 0, 0);
    }
}

// ---------------- MFMA GEMM: C[M,N] = A[M,K] @ BT[N,K]^T (+epilogue) --------
// MODE 0: leaky_relu(acc + bias[n])     -> OBF? bf16 : f32
// MODE 1: acc                           -> bf16
// MODE 3: acc + bias[n]*aux1[idx]       -> bf16      (ys = xsC + D*u)
// MODE 4: aux2[idx] += aux1[idx]*sigmoid(acc+bias[n]); optional bf16 copy aux3
template<int MODE, int OBF>
__global__ __launch_bounds__(256) void mgemm(
    const unsigned short* __restrict__ A, const unsigned short* __restrict__ BT,
    void* Cout, int M, int N, int K,
    const float* __restrict__ bias, const unsigned short* __restrict__ aux1,
    float* aux2, unsigned short* aux3)
{
    __shared__ unsigned short smA[128 * 32];
    __shared__ unsigned short smB[128 * 32];
    int tid = threadIdx.x;
    int lane = tid & 63, w = tid >> 6;
    int wr = w & 1, wc = w >> 1;
    int m16 = lane & 15, quad = lane >> 4;
    int m0 = blockIdx.x * 128, n0 = blockIdx.y * 128;

    f32x4 acc[4][4] = {};

    for (int k0 = 0; k0 < K; k0 += 32) {
        stage_tile(A, K, m0, k0, smA, tid);
        stage_tile(BT, K, n0, k0, smB, tid);
        __syncthreads();
        bf16x8 af[4], bfr[4];
#pragma unroll
        for (int mi = 0; mi < 4; ++mi)
            af[mi] = *(const bf16x8*)(smA + (wr * 64 + mi * 16 + m16) * 32 + quad * 8);
#pragma unroll
        for (int nj = 0; nj < 4; ++nj)
            bfr[nj] = *(const bf16x8*)(smB + (wc * 64 + nj * 16 + m16) * 32 + quad * 8);
#pragma unroll
        for (int mi = 0; mi < 4; ++mi)
#pragma unroll
            for (int nj = 0; nj < 4; ++nj)
                acc[mi][nj] = __builtin_amdgcn_mfma_f32_16x16x32_bf16(
                    af[mi], bfr[nj], acc[mi][nj], 0, 0, 0);
        __syncthreads();
    }

#pragma unroll
    for (int mi = 0; mi < 4; ++mi) {
#pragma unroll
        for (int nj = 0; nj < 4; ++nj) {
            int mg = m0 + wr * 64 + mi * 16 + quad * 4;
            int ng = n0 + wc * 64 + nj * 16 + m16;
            float bn = (MODE == 1) ? 0.f : bias[ng];
#pragma unroll
            for (int r = 0; r < 4; ++r) {
                int row = mg + r;
                size_t idx = (size_t)row * N + ng;
                float v = acc[mi][nj][r];
                if (MODE == 0) {
                    v += bn; v = v > 0.f ? v : 0.01f * v;
                    if (OBF) ((unsigned short*)Cout)[idx] = f2bf(v);
                    else     ((float*)Cout)[idx] = v;
                } else if (MODE == 1) {
                    ((unsigned short*)Cout)[idx] = f2bf(v);
                } else if (MODE == 3) {
                    v += bn * bf2f(aux1[idx]);
                    ((unsigned short*)Cout)[idx] = f2bf(v);
                } else if (MODE == 4) {
                    float s = 1.f / (1.f + expf(-(v + bn)));
                    float x = aux2[idx] + bf2f(aux1[idx]) * s;
                    aux2[idx] = x;
                    if (aux3) aux3[idx] = f2bf(x);
                }
            }
        }
    }
}

// ---------------- LayerNorm (one wave per row of 256) -> bf16 ----------------
template<int GELU, typename TIN>
__global__ __launch_bounds__(256) void ln_k(const TIN* __restrict__ in,
    unsigned short* __restrict__ out,
    const float* __restrict__ scale, const float* __restrict__ bias)
{
    int wid = threadIdx.x >> 6, lane = threadIdx.x & 63;
    size_t row = (size_t)blockIdx.x * 4 + wid;
    float x[4];
    if (sizeof(TIN) == 4) {
        float4 v = ((const float4*)((const float*)in + row * 256))[lane];
        x[0] = v.x; x[1] = v.y; x[2] = v.z; x[3] = v.w;
    } else {
        ushort4 v = ((const ushort4*)((const unsigned short*)in + row * 256))[lane];
        x[0] = bf2f(v.x); x[1] = bf2f(v.y); x[2] = bf2f(v.z); x[3] = bf2f(v.w);
    }
    float s = x[0] + x[1] + x[2] + x[3];
#pragma unroll
    for (int off = 32; off; off >>= 1) s += __shfl_xor(s, off);
    float mu = s * (1.f / 256.f);
    float d0 = x[0] - mu, d1 = x[1] - mu, d2 = x[2] - mu, d3 = x[3] - mu;
    float q = d0 * d0 + d1 * d1 + d2 * d2 + d3 * d3;
#pragma unroll
    for (int off = 32; off; off >>= 1) q += __shfl_xor(q, off);
    float rstd = rsqrtf(q * (1.f / 256.f) + 1e-6f);
    float4 sc = ((const float4*)scale)[lane];
    float4 bi = ((const float4*)bias)[lane];
    float o0 = d0 * rstd * sc.x + bi.x;
    float o1 = d1 * rstd * sc.y + bi.y;
    float o2 = d2 * rstd * sc.z + bi.z;
    float o3 = d3 * rstd * sc.w + bi.w;
    if (GELU) { o0 = gelu_f(o0); o1 = gelu_f(o1); o2 = gelu_f(o2); o3 = gelu_f(o3); }
    ushort4 ov = { f2bf(o0), f2bf(o1), f2bf(o2), f2bf(o3) };
    ((ushort4*)(out + row * 256))[lane] = ov;
}

// ---------------- Sequential scan over T, one thread per (b,p) chain --------
__global__ __launch_bounds__(256) void scan_k(
    const unsigned short* __restrict__ bu, unsigned short* __restrict__ xs,
    const float* __restrict__ dones,
    const float* __restrict__ h0re, const float* __restrict__ h0im,
    const float* __restrict__ lamre, const float* __restrict__ lamim,
    const float* __restrict__ lstep, float* __restrict__ outre, float* __restrict__ outim)
{
    int gid = blockIdx.x * 256 + threadIdx.x;
    int b = gid >> 7, p = gid & 127;
    float lr = lamre[p], li = lamim[p];
    float st = expf(lstep[p]);
    float er = expf(lr * st);
    float ar = er * cosf(li * st);
    float ai = er * sinf(li * st);
    float hr = h0re[gid], hi = h0im[gid];
    unsigned short cbr[4] = {}, cbi[4] = {};
    float cdn[4] = {};
#pragma unroll
    for (int j = 0; j < 4; ++j) {
        size_t base = ((size_t)j * BB + b) * 256;
        cbr[j] = bu[base + p]; cbi[j] = bu[base + 128 + p];
        cdn[j] = dones[j * BB + b];
    }
    for (int t0 = 0; t0 < TT; t0 += 4) {
        unsigned short nbr[4] = {}, nbi[4] = {};
        float ndn[4] = {};
        if (t0 + 4 < TT) {
#pragma unroll
            for (int j = 0; j < 4; ++j) {
                size_t base = ((size_t)(t0 + 4 + j) * BB + b) * 256;
                nbr[j] = bu[base + p]; nbi[j] = bu[base + 128 + p];
                ndn[j] = dones[(t0 + 4 + j) * BB + b];
            }
        }
#pragma unroll
        for (int j = 0; j < 4; ++j) {
            float brf = bf2f(cbr[j]), bif = bf2f(cbi[j]);
            float nr, ni;
            if (cdn[j] != 0.f) { nr = brf; ni = bif; }
            else {
                nr = fmaf(ar, hr, fmaf(-ai, hi, brf));
                ni = fmaf(ar, hi, fmaf(ai, hr, bif));
            }
            hr = nr; hi = ni;
            size_t base = ((size_t)(t0 + j) * BB + b) * 256;
            xs[base + p] = f2bf(nr);
            xs[base + 128 + p] = f2bf(ni);
        }
#pragma unroll
        for (int j = 0; j < 4; ++j) { cbr[j] = nbr[j]; cbi[j] = nbi[j]; cdn[j] = ndn[j]; }
    }
    outre[gid] = hr;
    outim[gid] = hi;
}

// -------- Precompute B_barT [n=2P][k=H] and CcatT [n=H][k=2P] in bf16 --------
__global__ __launch_bounds__(256) void prep_k(
    const float* __restrict__ Br, const float* __restrict__ Bi,
    const float* __restrict__ Cr, const float* __restrict__ Ci,
    const float* __restrict__ Lr, const float* __restrict__ Li,
    const float* __restrict__ ls, unsigned short* bbarT, unsigned short* ccatT)
{
    int gid = blockIdx.x * 256 + threadIdx.x;   // L*P*H = 131072
    int l = gid >> 15;
    int rem = gid & 32767;
    int p = rem >> 8;
    int h = rem & 255;
    float lr = Lr[l * PD + p], li = Li[l * PD + p];
    float st = expf(ls[l * PD + p]);
    float er = expf(lr * st);
    float lbr = er * cosf(li * st);
    float lbi = er * sinf(li * st);
    float nr = lbr - 1.f, ni = lbi;
    float den = lr * lr + li * li;
    float fr = (nr * lr + ni * li) / den;
    float fi = (ni * lr - nr * li) / den;
    float bre = Br[(size_t)(l * PD + p) * HD + h];
    float bim = Bi[(size_t)(l * PD + p) * HD + h];
    size_t lb = (size_t)l * 65536;
    bbarT[lb + (size_t)p * 256 + h]         = f2bf(fr * bre - fi * bim);
    bbarT[lb + (size_t)(128 + p) * 256 + h] = f2bf(fr * bim + fi * bre);
    float cre = Cr[(size_t)(l * HD + h) * PD + p];
    float cim = Ci[(size_t)(l * HD + h) * PD + p];
    ccatT[lb + (size_t)h * 256 + p]         = f2bf(2.f * cre);
    ccatT[lb + (size_t)h * 256 + 128 + p]   = f2bf(-2.f * cim);
}

// -------- transpose+convert: in f32 [K][N] -> out bf16 [N][K] ---------------
__global__ __launch_bounds__(256) void tcvt_k(const float* __restrict__ in,
    unsigned short* __restrict__ out, int K, int N)
{
    int gid = blockIdx.x * 256 + threadIdx.x;
    if (gid >= K * N) return;
    int k = gid / N, n = gid - k * N;
    out[(size_t)n * K + k] = f2bf(in[gid]);
}

// -------- straight convert f32 -> bf16, 4 elements / thread -----------------
__global__ __launch_bounds__(256) void cvt_k(const float* __restrict__ in,
    unsigned short* __restrict__ out)
{
    size_t gid = (size_t)blockIdx.x * 256 + threadIdx.x;
    float4 v = ((const float4*)in)[gid];
    ushort4 o = { f2bf(v.x), f2bf(v.y), f2bf(v.z), f2bf(v.w) };
    ((ushort4*)out)[gid] = o;
}

// ---------------- Final heads: wave per row -> out[row*9 + ...] -------------
__global__ __launch_bounds__(256) void head_k(
    const float* __restrict__ am2, const float* __restrict__ v2,
    const float* __restrict__ adW, const float* __restrict__ adb,
    const float* __restrict__ lstd,
    const float* __restrict__ vdW, const float* __restrict__ vdb,
    float* out)
{
    int wid = threadIdx.x >> 6, lane = threadIdx.x & 63;
    size_t row = (size_t)blockIdx.x * 4 + wid;
    float a1 = am2[row * 128 + lane];
    float a2 = am2[row * 128 + 64 + lane];
    float w1 = v2[row * 128 + lane];
    float w2 = v2[row * 128 + 64 + lane];
    float vals[5];
#pragma unroll
    for (int a = 0; a < 4; ++a)
        vals[a] = a1 * adW[lane * 4 + a] + a2 * adW[(lane + 64) * 4 + a];
    vals[4] = w1 * vdW[lane] + w2 * vdW[64 + lane];
#pragma unroll
    for (int off = 32; off; off >>= 1)
#pragma unroll
        for (int k = 0; k < 5; ++k) vals[k] += __shfl_xor(vals[k], off);
    if (lane == 0) {
        size_t o = row * 9;
#pragma unroll
        for (int a = 0; a < 4; ++a) out[o + a] = vals[a] + adb[a];
#pragma unroll
        for (int a = 0; a < 4; ++a) out[o + 4 + a] = expf(lstd[a]);
        out[o + 8] = vals[4] + vdb[0];
    }
}

extern "C" void kernel_launch(void* const* d_in, const int* in_sizes, int n_in,
                              void* d_out, int out_size, void* d_ws, size_t ws_size,
                              hipStream_t stream) {
    (void)in_sizes; (void)n_in; (void)out_size; (void)ws_size;
    const float* obs     = (const float*)d_in[0];
    const float* dones   = (const float*)d_in[1];
    const float* hre     = (const float*)d_in[2];
    const float* him     = (const float*)d_in[3];
    const float* enc0_W  = (const float*)d_in[4];
    const float* enc0_b  = (const float*)d_in[5];
    const float* enc1_W  = (const float*)d_in[6];
    const float* enc1_b  = (const float*)d_in[7];
    const float* nsc     = (const float*)d_in[8];
    const float* nbi     = (const float*)d_in[9];
    const float* Lre     = (const float*)d_in[10];
    const float* Lim     = (const float*)d_in[11];
    const float* B_re    = (const float*)d_in[12];
    const float* B_im    = (const float*)d_in[13];
    const float* C_re    = (const float*)d_in[14];
    const float* C_im    = (const float*)d_in[15];
    const float* Dv      = (const float*)d_in[16];
    const float* lstep   = (const float*)d_in[17];
    const float* glu_W   = (const float*)d_in[18];
    const float* glu_b   = (const float*)d_in[19];
    const float* ab0_W   = (const float*)d_in[20];
    const float* ab0_b   = (const float*)d_in[21];
    const float* ab1_W   = (const float*)d_in[22];
    const float* ab1_b   = (const float*)d_in[23];
    const float* adec_W  = (const float*)d_in[24];
    const float* adec_b  = (const float*)d_in[25];
    const float* log_std = (const float*)d_in[26];
    const float* vb0_W   = (const float*)d_in[27];
    const float* vb0_b   = (const float*)d_in[28];
    const float* vb1_W   = (const float*)d_in[29];
    const float* vb1_b   = (const float*)d_in[30];
    const float* vdec_W  = (const float*)d_in[31];
    const float* vdec_b  = (const float*)d_in[32];

    const size_t MB = (size_t)1 << 20;
    char* wsb = (char*)d_ws;
    // regions (total ~194 MB):
    unsigned short* OBSBF = (unsigned short*)(wsb);              // 64MB (encoder only)
    unsigned short* XS    = (unsigned short*)(wsb);              // 32MB (per-layer xs)
    unsigned short* YS    = (unsigned short*)(wsb + 32 * MB);    // 32MB (per-layer ys)
    unsigned short* XBF   = (unsigned short*)(wsb);              // 32MB (after layers)
    unsigned short* AM1   = (unsigned short*)(wsb + 32 * MB);    // 16MB
    unsigned short* V1    = (unsigned short*)(wsb + 48 * MB);    // 16MB
    unsigned short* U     = (unsigned short*)(wsb + 64 * MB);    // 32MB (u / z)
    float*          X     = (float*)(wsb + 96 * MB);             // 64MB residual f32
    unsigned short* BU    = (unsigned short*)(wsb + 160 * MB);   // 32MB (Bu)
    float*          AM2   = (float*)(wsb + 160 * MB);            // 32MB (after layers)
    float*          V2    = (float*)(wsb + 64 * MB);             // 32MB (after layers)
    char* wgt = wsb + 192 * MB;
    unsigned short* BBART = (unsigned short*)(wgt);              // 512KB
    unsigned short* CCATT = (unsigned short*)(wgt + 512 * 1024);
    unsigned short* GLUT  = (unsigned short*)(wgt + 1024 * 1024);
    unsigned short* E0T   = (unsigned short*)(wgt + 1536 * 1024);
    unsigned short* E1T   = (unsigned short*)(wgt + 1664 * 1024);
    unsigned short* AB0T  = (unsigned short*)(wgt + 1728 * 1024);
    unsigned short* AB1T  = (unsigned short*)(wgt + 1792 * 1024);
    unsigned short* VB0T  = (unsigned short*)(wgt + 1824 * 1024);
    unsigned short* VB1T  = (unsigned short*)(wgt + 1888 * 1024);

    float* out   = (float*)d_out;
    float* outre = out + (size_t)NTB * 9;
    float* outim = outre + LD * BB * PD;

    // ---- weight prep ----
    prep_k<<<512, 256, 0, stream>>>(B_re, B_im, C_re, C_im, Lre, Lim, lstep, BBART, CCATT);
    tcvt_k<<<256, 256, 0, stream>>>(enc0_W, E0T, 512, 128);
    tcvt_k<<<128, 256, 0, stream>>>(enc1_W, E1T, 128, 256);
    for (int l = 0; l < LD; ++l)
        tcvt_k<<<256, 256, 0, stream>>>(glu_W + (size_t)l * 65536, GLUT + (size_t)l * 65536, 256, 256);
    tcvt_k<<<128, 256, 0, stream>>>(ab0_W, AB0T, 256, 128);
    tcvt_k<<<64, 256, 0, stream>>>(ab1_W, AB1T, 128, 128);
    tcvt_k<<<128, 256, 0, stream>>>(vb0_W, VB0T, 256, 128);
    tcvt_k<<<64, 256, 0, stream>>>(vb1_W, VB1T, 128, 128);
    cvt_k<<<32768, 256, 0, stream>>>(obs, OBSBF);   // 33.5M elements

    // ---- encoder ----
    mgemm<0, 1><<<dim3(512, 1), 256, 0, stream>>>(OBSBF, E0T, U, NTB, 128, 512, enc0_b, nullptr, nullptr, nullptr);
    mgemm<0, 0><<<dim3(512, 2), 256, 0, stream>>>(U, E1T, X, NTB, 256, 128, enc1_b, nullptr, nullptr, nullptr);

    // ---- S5 layers ----
    for (int l = 0; l < LD; ++l) {
        const float* sc = nsc + l * HD;
        const float* bi = nbi + l * HD;
        ln_k<0, float><<<NTB / 4, 256, 0, stream>>>(X, U, sc, bi);
        mgemm<1, 1><<<dim3(512, 2), 256, 0, stream>>>(U, BBART + (size_t)l * 65536, BU, NTB, 256, 256, nullptr, nullptr, nullptr, nullptr);
        scan_k<<<64, 256, 0, stream>>>(BU, XS, dones, hre + l * BB * PD, him + l * BB * PD,
                                       Lre + l * PD, Lim + l * PD, lstep + l * PD,
                                       outre + l * BB * PD, outim + l * BB * PD);
        mgemm<3, 1><<<dim3(512, 2), 256, 0, stream>>>(XS, CCATT + (size_t)l * 65536, YS, NTB, 256, 256, Dv + l * HD, U, nullptr, nullptr);
        ln_k<1, unsigned short><<<NTB / 4, 256, 0, stream>>>(YS, U, sc, bi);
        mgemm<4, 0><<<dim3(512, 2), 256, 0, stream>>>(U, GLUT + (size_t)l * 65536, nullptr, NTB, 256, 256,
                                                      glu_b + l * HD, U, X, (l == 3) ? XBF : nullptr);
    }

    // ---- heads ----
    mgemm<0, 1><<<dim3(512, 1), 256, 0, stream>>>(XBF, AB0T, AM1, NTB, 128, 256, ab0_b, nullptr, nullptr, nullptr);
    mgemm<0, 0><<<dim3(512, 1), 256, 0, stream>>>(AM1, AB1T, AM2, NTB, 128, 128, ab1_b, nullptr, nullptr, nullptr);
    mgemm<0, 1><<<dim3(512, 1), 256, 0, stream>>>(XBF, VB0T, V1, NTB, 128, 256, vb0_b, nullptr, nullptr, nullptr);
    mgemm<0, 0><<<dim3(512, 1), 256, 0, stream>>>(V1, VB1T, V2, NTB, 128, 128, vb1_b, nullptr, nullptr, nullptr);
    head_k<<<NTB / 4, 256, 0, stream>>>(AM2, V2, adec_W, adec_b, log_std, vdec_W, vdec_b, out);
}

// Round 3
// 1236.090 us; speedup vs baseline: 2.1933x; 1.1003x over previous
//
#include <hip/hip_runtime.h>
#include <math.h>

#define TT 512
#define BB 128
#define OBSD 512
#define HD 256
#define PD 128
#define LD 4
#define NTB (TT*BB)   // 65536

typedef __bf16 bf16x8 __attribute__((ext_vector_type(8)));
typedef float  f32x4  __attribute__((ext_vector_type(4)));

__device__ __forceinline__ float bf2f(unsigned short u) {
    return __uint_as_float(((unsigned)u) << 16);
}
__device__ __forceinline__ unsigned short f2bf(float f) {
    unsigned u = __float_as_uint(f);
    unsigned r = (u + 0x7FFFu + ((u >> 16) & 1u)) >> 16;
    return (unsigned short)r;
}
__device__ __forceinline__ float gelu_f(float x) {
    float x3 = x * x * x;
    return 0.5f * x * (1.f + tanhf(0.7978845608028654f * (x + 0.044715f * x3)));
}

// ---- stage a 128x32 bf16 tile (row-major, 64B rows) into LDS via global_load_lds ----
__device__ __forceinline__ void stage_tile(const unsigned short* gbase, int ldk,
                                           int row0, int k0, unsigned short* sm, int tid)
{
    int w = tid >> 6, lane = tid & 63;
#pragma unroll
    for (int p = 0; p < 2; ++p) {
        int r = p * 64 + w * 16 + (lane >> 2);
        const unsigned short* g = gbase + (size_t)(row0 + r) * ldk + k0 + (lane & 3) * 8;
        unsigned short* l = sm + (p * 64 + w * 16) * 32;
        __builtin_amdgcn_global_load_lds(
            (const __attribute__((address_space(1))) void*)g,
            (__attribute__((address_space(3))) void*)l, 16, 0, 0);
    }
}

// ---------------- MFMA GEMM: C[M,N] = A[M,K] @ BT[N,K]^T (+epilogue) --------
// MODE 0: leaky_relu(acc + bias[n])     -> OBF? bf16 : f32 (+opt bf16 aux3)
// MODE 1: acc                           -> bf16
// MODE 3: acc + bias[n]*aux1[idx]       -> bf16      (ys = xsC + D*u)
// MODE 4: aux2[idx] += aux1[idx]*sigmoid(acc+bias[n]); bf16 copy to aux3
template<int MODE, int OBF>
__global__ __launch_bounds__(256) void mgemm(
    const unsigned short* __restrict__ A, const unsigned short* __restrict__ BT,
    void* Cout, int M, int N, int K,
    const float* __restrict__ bias, const unsigned short* __restrict__ aux1,
    float* aux2, unsigned short* aux3)
{
    __shared__ unsigned short smA[128 * 32];
    __shared__ unsigned short smB[128 * 32];
    int tid = threadIdx.x;
    int lane = tid & 63, w = tid >> 6;
    int wr = w & 1, wc = w >> 1;
    int m16 = lane & 15, quad = lane >> 4;
    int m0 = blockIdx.x * 128, n0 = blockIdx.y * 128;

    f32x4 acc[4][4] = {};

    for (int k0 = 0; k0 < K; k0 += 32) {
        stage_tile(A, K, m0, k0, smA, tid);
        stage_tile(BT, K, n0, k0, smB, tid);
        __syncthreads();
        bf16x8 af[4], bfr[4];
#pragma unroll
        for (int mi = 0; mi < 4; ++mi)
            af[mi] = *(const bf16x8*)(smA + (wr * 64 + mi * 16 + m16) * 32 + quad * 8);
#pragma unroll
        for (int nj = 0; nj < 4; ++nj)
            bfr[nj] = *(const bf16x8*)(smB + (wc * 64 + nj * 16 + m16) * 32 + quad * 8);
#pragma unroll
        for (int mi = 0; mi < 4; ++mi)
#pragma unroll
            for (int nj = 0; nj < 4; ++nj)
                acc[mi][nj] = __builtin_amdgcn_mfma_f32_16x16x32_bf16(
                    af[mi], bfr[nj], acc[mi][nj], 0, 0, 0);
        __syncthreads();
    }

#pragma unroll
    for (int mi = 0; mi < 4; ++mi) {
#pragma unroll
        for (int nj = 0; nj < 4; ++nj) {
            int mg = m0 + wr * 64 + mi * 16 + quad * 4;
            int ng = n0 + wc * 64 + nj * 16 + m16;
            float bn = (MODE == 1) ? 0.f : bias[ng];
#pragma unroll
            for (int r = 0; r < 4; ++r) {
                int row = mg + r;
                size_t idx = (size_t)row * N + ng;
                float v = acc[mi][nj][r];
                if (MODE == 0) {
                    v += bn; v = v > 0.f ? v : 0.01f * v;
                    if (OBF) ((unsigned short*)Cout)[idx] = f2bf(v);
                    else {
                        ((float*)Cout)[idx] = v;
                        if (aux3) aux3[idx] = f2bf(v);
                    }
                } else if (MODE == 1) {
                    ((unsigned short*)Cout)[idx] = f2bf(v);
                } else if (MODE == 3) {
                    v += bn * bf2f(aux1[idx]);
                    ((unsigned short*)Cout)[idx] = f2bf(v);
                } else if (MODE == 4) {
                    float s = 1.f / (1.f + expf(-(v + bn)));
                    float x = aux2[idx] + bf2f(aux1[idx]) * s;
                    aux2[idx] = x;
                    if (aux3) aux3[idx] = f2bf(x);
                }
            }
        }
    }
}

// ---------------- LayerNorm (one wave per row of 256), bf16 in/out ----------
template<int GELU>
__global__ __launch_bounds__(256) void ln_k(const unsigned short* __restrict__ in,
    unsigned short* __restrict__ out,
    const float* __restrict__ scale, const float* __restrict__ bias)
{
    int wid = threadIdx.x >> 6, lane = threadIdx.x & 63;
    size_t row = (size_t)blockIdx.x * 4 + wid;
    ushort4 v = ((const ushort4*)(in + row * 256))[lane];
    float x0 = bf2f(v.x), x1 = bf2f(v.y), x2 = bf2f(v.z), x3 = bf2f(v.w);
    float s = x0 + x1 + x2 + x3;
#pragma unroll
    for (int off = 32; off; off >>= 1) s += __shfl_xor(s, off);
    float mu = s * (1.f / 256.f);
    float d0 = x0 - mu, d1 = x1 - mu, d2 = x2 - mu, d3 = x3 - mu;
    float q = d0 * d0 + d1 * d1 + d2 * d2 + d3 * d3;
#pragma unroll
    for (int off = 32; off; off >>= 1) q += __shfl_xor(q, off);
    float rstd = rsqrtf(q * (1.f / 256.f) + 1e-6f);
    float4 sc = ((const float4*)scale)[lane];
    float4 bi = ((const float4*)bias)[lane];
    float o0 = d0 * rstd * sc.x + bi.x;
    float o1 = d1 * rstd * sc.y + bi.y;
    float o2 = d2 * rstd * sc.z + bi.z;
    float o3 = d3 * rstd * sc.w + bi.w;
    if (GELU) { o0 = gelu_f(o0); o1 = gelu_f(o1); o2 = gelu_f(o2); o3 = gelu_f(o3); }
    ushort4 ov = { f2bf(o0), f2bf(o1), f2bf(o2), f2bf(o3) };
    ((ushort4*)(out + row * 256))[lane] = ov;
}

// ------------- Chunk-parallel scan: 256 blocks x 512 threads ----------------
// block = (b, p-half); thread = (chunk 0..7, pl 0..63); chunk covers 64 t's.
__global__ __launch_bounds__(512) void scan2_k(
    const unsigned short* __restrict__ bu, unsigned short* __restrict__ xs,
    const float* __restrict__ dones,
    const float* __restrict__ h0re, const float* __restrict__ h0im,
    const float* __restrict__ lamre, const float* __restrict__ lamim,
    const float* __restrict__ lstep,
    float* __restrict__ outre, float* __restrict__ outim)
{
    __shared__ float sdone[TT];
    __shared__ float4 ssum[8][64];
    __shared__ float2 shin[8][64];
    int tid = threadIdx.x;
    int b  = blockIdx.x >> 1;
    int ph = blockIdx.x & 1;
    int chunk = tid >> 6, pl = tid & 63;
    int p = ph * 64 + pl;
    sdone[tid] = dones[tid * BB + b];
    float lr = lamre[p], li = lamim[p];
    float st = expf(lstep[p]);
    float er = expf(lr * st);
    float ar = er * cosf(li * st);
    float ai = er * sinf(li * st);
    __syncthreads();

    int t0 = chunk * 64;
    unsigned buf[64];
    float Ar = 1.f, Ai = 0.f, br = 0.f, bi = 0.f;
#pragma unroll
    for (int j = 0; j < 64; ++j) {
        size_t base = ((size_t)(t0 + j) * BB + b) * 256;
        unsigned short rr = bu[base + p];
        unsigned short ii = bu[base + 128 + p];
        buf[j] = ((unsigned)ii << 16) | rr;
        float bur = bf2f(rr), bui = bf2f(ii);
        if (sdone[t0 + j] != 0.f) {
            Ar = 0.f; Ai = 0.f; br = bur; bi = bui;
        } else {
            float nAr = ar * Ar - ai * Ai;
            float nAi = ar * Ai + ai * Ar;
            float nbr = fmaf(ar, br, fmaf(-ai, bi, bur));
            float nbi = fmaf(ar, bi, fmaf(ai, br, bui));
            Ar = nAr; Ai = nAi; br = nbr; bi = nbi;
        }
    }
    ssum[chunk][pl] = float4{Ar, Ai, br, bi};
    __syncthreads();
    if (tid < 64) {
        int gid = b * 128 + p;
        float hr = h0re[gid], hi = h0im[gid];
#pragma unroll
        for (int c = 0; c < 8; ++c) {
            shin[c][pl] = float2{hr, hi};
            float4 s = ssum[c][pl];
            float nhr = fmaf(s.x, hr, fmaf(-s.y, hi, s.z));
            float nhi = fmaf(s.x, hi, fmaf(s.y, hr, s.w));
            hr = nhr; hi = nhi;
        }
        outre[gid] = hr; outim[gid] = hi;
    }
    __syncthreads();
    float hr = shin[chunk][pl].x, hi = shin[chunk][pl].y;
#pragma unroll
    for (int j = 0; j < 64; ++j) {
        unsigned v = buf[j];
        float bur = bf2f((unsigned short)(v & 0xFFFFu));
        float bui = bf2f((unsigned short)(v >> 16));
        float nr, ni;
        if (sdone[t0 + j] != 0.f) { nr = bur; ni = bui; }
        else {
            nr = fmaf(ar, hr, fmaf(-ai, hi, bur));
            ni = fmaf(ar, hi, fmaf(ai, hr, bui));
        }
        hr = nr; hi = ni;
        size_t base = ((size_t)(t0 + j) * BB + b) * 256;
        xs[base + p] = f2bf(nr);
        xs[base + 128 + p] = f2bf(ni);
    }
}

// -------- Precompute B_barT [n=2P][k=H] and CcatT [n=H][k=2P] in bf16 --------
__global__ __launch_bounds__(256) void prep_k(
    const float* __restrict__ Br, const float* __restrict__ Bi,
    const float* __restrict__ Cr, const float* __restrict__ Ci,
    const float* __restrict__ Lr, const float* __restrict__ Li,
    const float* __restrict__ ls, unsigned short* bbarT, unsigned short* ccatT)
{
    int gid = blockIdx.x * 256 + threadIdx.x;   // L*P*H = 131072
    int l = gid >> 15;
    int rem = gid & 32767;
    int p = rem >> 8;
    int h = rem & 255;
    float lr = Lr[l * PD + p], li = Li[l * PD + p];
    float st = expf(ls[l * PD + p]);
    float er = expf(lr * st);
    float lbr = er * cosf(li * st);
    float lbi = er * sinf(li * st);
    float nr = lbr - 1.f, ni = lbi;
    float den = lr * lr + li * li;
    float fr = (nr * lr + ni * li) / den;
    float fi = (ni * lr - nr * li) / den;
    float bre = Br[(size_t)(l * PD + p) * HD + h];
    float bim = Bi[(size_t)(l * PD + p) * HD + h];
    size_t lb = (size_t)l * 65536;
    bbarT[lb + (size_t)p * 256 + h]         = f2bf(fr * bre - fi * bim);
    bbarT[lb + (size_t)(128 + p) * 256 + h] = f2bf(fr * bim + fi * bre);
    float cre = Cr[(size_t)(l * HD + h) * PD + p];
    float cim = Ci[(size_t)(l * HD + h) * PD + p];
    ccatT[lb + (size_t)h * 256 + p]         = f2bf(2.f * cre);
    ccatT[lb + (size_t)h * 256 + 128 + p]   = f2bf(-2.f * cim);
}

// -------- transpose+convert: in f32 [K][N] -> out bf16 [N][K] ---------------
__global__ __launch_bounds__(256) void tcvt_k(const float* __restrict__ in,
    unsigned short* __restrict__ out, int K, int N)
{
    int gid = blockIdx.x * 256 + threadIdx.x;
    if (gid >= K * N) return;
    int k = gid / N, n = gid - k * N;
    out[(size_t)n * K + k] = f2bf(in[gid]);
}

// -------- straight convert f32 -> bf16, 4 elements / thread -----------------
__global__ __launch_bounds__(256) void cvt_k(const float* __restrict__ in,
    unsigned short* __restrict__ out)
{
    size_t gid = (size_t)blockIdx.x * 256 + threadIdx.x;
    float4 v = ((const float4*)in)[gid];
    ushort4 o = { f2bf(v.x), f2bf(v.y), f2bf(v.z), f2bf(v.w) };
    ((ushort4*)out)[gid] = o;
}

// ---------------- Final heads: wave per row -> out[row*9 + ...] -------------
__global__ __launch_bounds__(256) void head_k(
    const unsigned short* __restrict__ am2, const unsigned short* __restrict__ v2,
    const float* __restrict__ adW, const float* __restrict__ adb,
    const float* __restrict__ lstd,
    const float* __restrict__ vdW, const float* __restrict__ vdb,
    float* out)
{
    int wid = threadIdx.x >> 6, lane = threadIdx.x & 63;
    size_t row = (size_t)blockIdx.x * 4 + wid;
    float a1 = bf2f(am2[row * 128 + lane]);
    float a2 = bf2f(am2[row * 128 + 64 + lane]);
    float w1 = bf2f(v2[row * 128 + lane]);
    float w2 = bf2f(v2[row * 128 + 64 + lane]);
    float vals[5];
#pragma unroll
    for (int a = 0; a < 4; ++a)
        vals[a] = a1 * adW[lane * 4 + a] + a2 * adW[(lane + 64) * 4 + a];
    vals[4] = w1 * vdW[lane] + w2 * vdW[64 + lane];
#pragma unroll
    for (int off = 32; off; off >>= 1)
#pragma unroll
        for (int k = 0; k < 5; ++k) vals[k] += __shfl_xor(vals[k], off);
    if (lane == 0) {
        size_t o = row * 9;
#pragma unroll
        for (int a = 0; a < 4; ++a) out[o + a] = vals[a] + adb[a];
#pragma unroll
        for (int a = 0; a < 4; ++a) out[o + 4 + a] = expf(lstd[a]);
        out[o + 8] = vals[4] + vdb[0];
    }
}

extern "C" void kernel_launch(void* const* d_in, const int* in_sizes, int n_in,
                              void* d_out, int out_size, void* d_ws, size_t ws_size,
                              hipStream_t stream) {
    (void)in_sizes; (void)n_in; (void)out_size; (void)ws_size;
    const float* obs     = (const float*)d_in[0];
    const float* dones   = (const float*)d_in[1];
    const float* hre     = (const float*)d_in[2];
    const float* him     = (const float*)d_in[3];
    const float* enc0_W  = (const float*)d_in[4];
    const float* enc0_b  = (const float*)d_in[5];
    const float* enc1_W  = (const float*)d_in[6];
    const float* enc1_b  = (const float*)d_in[7];
    const float* nsc     = (const float*)d_in[8];
    const float* nbi     = (const float*)d_in[9];
    const float* Lre     = (const float*)d_in[10];
    const float* Lim     = (const float*)d_in[11];
    const float* B_re    = (const float*)d_in[12];
    const float* B_im    = (const float*)d_in[13];
    const float* C_re    = (const float*)d_in[14];
    const float* C_im    = (const float*)d_in[15];
    const float* Dv      = (const float*)d_in[16];
    const float* lstep   = (const float*)d_in[17];
    const float* glu_W   = (const float*)d_in[18];
    const float* glu_b   = (const float*)d_in[19];
    const float* ab0_W   = (const float*)d_in[20];
    const float* ab0_b   = (const float*)d_in[21];
    const float* ab1_W   = (const float*)d_in[22];
    const float* ab1_b   = (const float*)d_in[23];
    const float* adec_W  = (const float*)d_in[24];
    const float* adec_b  = (const float*)d_in[25];
    const float* log_std = (const float*)d_in[26];
    const float* vb0_W   = (const float*)d_in[27];
    const float* vb0_b   = (const float*)d_in[28];
    const float* vb1_W   = (const float*)d_in[29];
    const float* vb1_b   = (const float*)d_in[30];
    const float* vdec_W  = (const float*)d_in[31];
    const float* vdec_b  = (const float*)d_in[32];

    const size_t MB = (size_t)1 << 20;
    char* wsb = (char*)d_ws;
    unsigned short* OBSBF = (unsigned short*)(wsb);              // 64MB (encoder only)
    unsigned short* XS    = (unsigned short*)(wsb);              // 32MB (per-layer xs)
    unsigned short* XBF   = (unsigned short*)(wsb);              // 32MB (bf16 residual copy; alternates with XS)
    unsigned short* YS    = (unsigned short*)(wsb + 32 * MB);    // 32MB (per-layer ys)
    unsigned short* AM1   = (unsigned short*)(wsb + 32 * MB);    // 16MB
    unsigned short* V1    = (unsigned short*)(wsb + 48 * MB);    // 16MB
    unsigned short* U     = (unsigned short*)(wsb + 64 * MB);    // 32MB (u / z)
    unsigned short* V2    = (unsigned short*)(wsb + 64 * MB);    // (heads; U dead)
    float*          X     = (float*)(wsb + 96 * MB);             // 64MB residual f32
    unsigned short* BU    = (unsigned short*)(wsb + 160 * MB);   // 32MB (Bu)
    unsigned short* AM2   = (unsigned short*)(wsb + 160 * MB);   // (heads; BU dead)
    char* wgt = wsb + 192 * MB;
    unsigned short* BBART = (unsigned short*)(wgt);              // 512KB
    unsigned short* CCATT = (unsigned short*)(wgt + 512 * 1024);
    unsigned short* GLUT  = (unsigned short*)(wgt + 1024 * 1024);
    unsigned short* E0T   = (unsigned short*)(wgt + 1536 * 1024);
    unsigned short* E1T   = (unsigned short*)(wgt + 1664 * 1024);
    unsigned short* AB0T  = (unsigned short*)(wgt + 1728 * 1024);
    unsigned short* AB1T  = (unsigned short*)(wgt + 1792 * 1024);
    unsigned short* VB0T  = (unsigned short*)(wgt + 1824 * 1024);
    unsigned short* VB1T  = (unsigned short*)(wgt + 1888 * 1024);

    float* out   = (float*)d_out;
    float* outre = out + (size_t)NTB * 9;
    float* outim = outre + LD * BB * PD;

    // ---- weight prep ----
    prep_k<<<512, 256, 0, stream>>>(B_re, B_im, C_re, C_im, Lre, Lim, lstep, BBART, CCATT);
    tcvt_k<<<256, 256, 0, stream>>>(enc0_W, E0T, 512, 128);
    tcvt_k<<<128, 256, 0, stream>>>(enc1_W, E1T, 128, 256);
    for (int l = 0; l < LD; ++l)
        tcvt_k<<<256, 256, 0, stream>>>(glu_W + (size_t)l * 65536, GLUT + (size_t)l * 65536, 256, 256);
    tcvt_k<<<128, 256, 0, stream>>>(ab0_W, AB0T, 256, 128);
    tcvt_k<<<64, 256, 0, stream>>>(ab1_W, AB1T, 128, 128);
    tcvt_k<<<128, 256, 0, stream>>>(vb0_W, VB0T, 256, 128);
    tcvt_k<<<64, 256, 0, stream>>>(vb1_W, VB1T, 128, 128);
    cvt_k<<<32768, 256, 0, stream>>>(obs, OBSBF);

    // ---- encoder ----
    mgemm<0, 1><<<dim3(512, 1), 256, 0, stream>>>(OBSBF, E0T, U, NTB, 128, 512, enc0_b, nullptr, nullptr, nullptr);
    mgemm<0, 0><<<dim3(512, 2), 256, 0, stream>>>(U, E1T, X, NTB, 256, 128, enc1_b, nullptr, nullptr, XBF);

    // ---- S5 layers ----
    for (int l = 0; l < LD; ++l) {
        const float* sc = nsc + l * HD;
        const float* bi = nbi + l * HD;
        ln_k<0><<<NTB / 4, 256, 0, stream>>>(XBF, U, sc, bi);
        mgemm<1, 1><<<dim3(512, 2), 256, 0, stream>>>(U, BBART + (size_t)l * 65536, BU, NTB, 256, 256, nullptr, nullptr, nullptr, nullptr);
        scan2_k<<<256, 512, 0, stream>>>(BU, XS, dones, hre + l * BB * PD, him + l * BB * PD,
                                         Lre + l * PD, Lim + l * PD, lstep + l * PD,
                                         outre + l * BB * PD, outim + l * BB * PD);
        mgemm<3, 1><<<dim3(512, 2), 256, 0, stream>>>(XS, CCATT + (size_t)l * 65536, YS, NTB, 256, 256, Dv + l * HD, U, nullptr, nullptr);
        ln_k<1><<<NTB / 4, 256, 0, stream>>>(YS, U, sc, bi);
        mgemm<4, 0><<<dim3(512, 2), 256, 0, stream>>>(U, GLUT + (size_t)l * 65536, nullptr, NTB, 256, 256,
                                                      glu_b + l * HD, U, X, XBF);
    }

    // ---- heads ----
    mgemm<0, 1><<<dim3(512, 1), 256, 0, stream>>>(XBF, AB0T, AM1, NTB, 128, 256, ab0_b, nullptr, nullptr, nullptr);
    mgemm<0, 1><<<dim3(512, 1), 256, 0, stream>>>(AM1, AB1T, AM2, NTB, 128, 128, ab1_b, nullptr, nullptr, nullptr);
    mgemm<0, 1><<<dim3(512, 1), 256, 0, stream>>>(XBF, VB0T, V1, NTB, 128, 256, vb0_b, nullptr, nullptr, nullptr);
    mgemm<0, 1><<<dim3(512, 1), 256, 0, stream>>>(V1, VB1T, V2, NTB, 128, 128, vb1_b, nullptr, nullptr, nullptr);
    head_k<<<NTB / 4, 256, 0, stream>>>(AM2, V2, adec_W, adec_b, log_std, vdec_W, vdec_b, out);
}

// Round 4
// 1003.658 us; speedup vs baseline: 2.7013x; 1.2316x over previous
//
#include <hip/hip_runtime.h>
#include <math.h>

#define TT 512
#define BB 128
#define OBSD 512
#define HD 256
#define PD 128
#define LD 4
#define NTB (TT*BB)   // 65536

typedef __bf16 bf16x8 __attribute__((ext_vector_type(8)));
typedef float  f32x4  __attribute__((ext_vector_type(4)));

__device__ __forceinline__ float bf2f(unsigned short u) {
    return __uint_as_float(((unsigned)u) << 16);
}
__device__ __forceinline__ unsigned short f2bf(float f) {
    unsigned u = __float_as_uint(f);
    unsigned r = (u + 0x7FFFu + ((u >> 16) & 1u)) >> 16;
    return (unsigned short)r;
}
__device__ __forceinline__ float gelu_f(float x) {
    float x3 = x * x * x;
    return 0.5f * x * (1.f + tanhf(0.7978845608028654f * (x + 0.044715f * x3)));
}

// ---- stage 128x32 bf16 tile via global_load_lds (4-wave / 256-thr block) ----
__device__ __forceinline__ void stage_tile4(const unsigned short* gbase, int ldk,
                                            int row0, int k0, unsigned short* sm, int tid)
{
    int w = tid >> 6, lane = tid & 63;
#pragma unroll
    for (int p = 0; p < 2; ++p) {
        int r = p * 64 + w * 16 + (lane >> 2);
        const unsigned short* g = gbase + (size_t)(row0 + r) * ldk + k0 + (lane & 3) * 8;
        unsigned short* l = sm + (p * 64 + w * 16) * 32;
        __builtin_amdgcn_global_load_lds(
            (const __attribute__((address_space(1))) void*)g,
            (__attribute__((address_space(3))) void*)l, 16, 0, 0);
    }
}

// ---- stage 128x32 tile, 512-thread block: one x4 load per thread -----------
__device__ __forceinline__ void stage_tile8(const unsigned short* gbase, int ldk,
                                            int row0, int k0, unsigned short* sm, int tid)
{
    int w = tid >> 6, lane = tid & 63;
    int r = w * 16 + (lane >> 2);
    const unsigned short* g = gbase + (size_t)(row0 + r) * ldk + k0 + (lane & 3) * 8;
    unsigned short* l = sm + w * 16 * 32;
    __builtin_amdgcn_global_load_lds(
        (const __attribute__((address_space(1))) void*)g,
        (__attribute__((address_space(3))) void*)l, 16, 0, 0);
}
// ---- stage 256x32 tile, 512-thread block: two x4 loads per thread ----------
__device__ __forceinline__ void stage_tile8w(const unsigned short* gbase, int ldk,
                                             int row0, int k0, unsigned short* sm, int tid)
{
    int w = tid >> 6, lane = tid & 63;
#pragma unroll
    for (int p = 0; p < 2; ++p) {
        int r = p * 128 + w * 16 + (lane >> 2);
        const unsigned short* g = gbase + (size_t)(row0 + r) * ldk + k0 + (lane & 3) * 8;
        unsigned short* l = sm + (p * 128 + w * 16) * 32;
        __builtin_amdgcn_global_load_lds(
            (const __attribute__((address_space(1))) void*)g,
            (__attribute__((address_space(3))) void*)l, 16, 0, 0);
    }
}

// ============ Fused GEMM, tile 128x256 (full N), 512 threads ================
// C[M,256] = A[M,K] @ BT[256,K]^T, then per-row LayerNorm fused in epilogue.
// MODE 0 (enc1): x = leaky(acc+bias);       write X; u = LN(x)          -> U
// MODE 1 (Bu):   write bf(acc)                                          -> U
// MODE 2 (ys):   v = acc + bias[c]*aux1;    z = gelu(LN(v))             -> U
// MODE 3 (GLU):  x = Xold + aux1*sigmoid(acc+bias); write X; u = LN(x)  -> U (if wU)
template<int MODE>
__global__ __launch_bounds__(512) void mgemm2(
    const unsigned short* __restrict__ A, const unsigned short* __restrict__ BT,
    int K, const float* __restrict__ bias,
    const float* __restrict__ lnsc, const float* __restrict__ lnbi,
    const unsigned short* __restrict__ aux1, unsigned short* Xio,
    unsigned short* __restrict__ U, int wU)
{
    __shared__ unsigned short smA[128 * 32];
    __shared__ unsigned short smB[256 * 32];
    __shared__ float2 red[128][4];
    int tid = threadIdx.x;
    int lane = tid & 63, w = tid >> 6;
    int wr = w & 1, wc = w >> 1;            // wr: row half, wc: col quarter
    int m16 = lane & 15, quad = lane >> 4;
    int m0 = blockIdx.x * 128;

    f32x4 acc[4][4] = {};

    for (int k0 = 0; k0 < K; k0 += 32) {
        stage_tile8(A, K, m0, k0, smA, tid);
        stage_tile8w(BT, K, 0, k0, smB, tid);
        __syncthreads();
        bf16x8 af[4], bfr[4];
#pragma unroll
        for (int mi = 0; mi < 4; ++mi)
            af[mi] = *(const bf16x8*)(smA + (wr * 64 + mi * 16 + m16) * 32 + quad * 8);
#pragma unroll
        for (int nj = 0; nj < 4; ++nj)
            bfr[nj] = *(const bf16x8*)(smB + (wc * 64 + nj * 16 + m16) * 32 + quad * 8);
#pragma unroll
        for (int mi = 0; mi < 4; ++mi)
#pragma unroll
            for (int nj = 0; nj < 4; ++nj)
                acc[mi][nj] = __builtin_amdgcn_mfma_f32_16x16x32_bf16(
                    af[mi], bfr[nj], acc[mi][nj], 0, 0, 0);
        __syncthreads();
    }

    int colb = wc * 64 + m16;   // col for nj=0
    if (MODE == 1) {
#pragma unroll
        for (int mi = 0; mi < 4; ++mi)
#pragma unroll
            for (int nj = 0; nj < 4; ++nj)
#pragma unroll
                for (int r = 0; r < 4; ++r) {
                    int row = m0 + wr * 64 + mi * 16 + quad * 4 + r;
                    U[(size_t)row * 256 + colb + nj * 16] = f2bf(acc[mi][nj][r]);
                }
        return;
    }

    float bn[4];
#pragma unroll
    for (int nj = 0; nj < 4; ++nj) bn[nj] = bias[colb + nj * 16];

    // ---- phase 1: transform acc -> v, write X, accumulate row stats ----
#pragma unroll
    for (int mi = 0; mi < 4; ++mi) {
#pragma unroll
        for (int r = 0; r < 4; ++r) {
            int row_l = wr * 64 + mi * 16 + quad * 4 + r;
            size_t rowb = (size_t)(m0 + row_l) * 256;
            float s = 0.f, q = 0.f;
#pragma unroll
            for (int nj = 0; nj < 4; ++nj) {
                size_t idx = rowb + colb + nj * 16;
                float v = acc[mi][nj][r];
                if (MODE == 0) {
                    v += bn[nj]; v = v > 0.f ? v : 0.01f * v;
                    Xio[idx] = f2bf(v);
                } else if (MODE == 2) {
                    v += bn[nj] * bf2f(aux1[idx]);
                } else if (MODE == 3) {
                    float sg = 1.f / (1.f + expf(-(v + bn[nj])));
                    v = bf2f(Xio[idx]) + bf2f(aux1[idx]) * sg;
                    Xio[idx] = f2bf(v);
                }
                acc[mi][nj][r] = v;
                s += v; q += v * v;
            }
            if (MODE != 3 || wU) {
#pragma unroll
                for (int mask = 1; mask < 16; mask <<= 1) {
                    s += __shfl_xor(s, mask);
                    q += __shfl_xor(q, mask);
                }
                if (m16 == 0) red[row_l][wc] = float2{s, q};
            }
        }
    }
    if (MODE == 3 && !wU) return;
    __syncthreads();

    // ---- phase 2: finalize LN, write U ----
    float ls[4], lb[4];
#pragma unroll
    for (int nj = 0; nj < 4; ++nj) { ls[nj] = lnsc[colb + nj * 16]; lb[nj] = lnbi[colb + nj * 16]; }
#pragma unroll
    for (int mi = 0; mi < 4; ++mi) {
#pragma unroll
        for (int r = 0; r < 4; ++r) {
            int row_l = wr * 64 + mi * 16 + quad * 4 + r;
            float2 t0 = red[row_l][0], t1 = red[row_l][1], t2 = red[row_l][2], t3 = red[row_l][3];
            float S = t0.x + t1.x + t2.x + t3.x;
            float Q = t0.y + t1.y + t2.y + t3.y;
            float mu = S * (1.f / 256.f);
            float var = Q * (1.f / 256.f) - mu * mu;
            float rstd = rsqrtf(var + 1e-6f);
            size_t rowb = (size_t)(m0 + row_l) * 256;
#pragma unroll
            for (int nj = 0; nj < 4; ++nj) {
                float o = (acc[mi][nj][r] - mu) * rstd * ls[nj] + lb[nj];
                if (MODE == 2) o = gelu_f(o);
                U[rowb + colb + nj * 16] = f2bf(o);
            }
        }
    }
}

// ============ Plain GEMM 128x128 tile (N=128 GEMMs): leaky(acc+bias) ========
__global__ __launch_bounds__(256) void mgemm(
    const unsigned short* __restrict__ A, const unsigned short* __restrict__ BT,
    unsigned short* __restrict__ C, int M, int N, int K,
    const float* __restrict__ bias)
{
    __shared__ unsigned short smA[128 * 32];
    __shared__ unsigned short smB[128 * 32];
    int tid = threadIdx.x;
    int lane = tid & 63, w = tid >> 6;
    int wr = w & 1, wc = w >> 1;
    int m16 = lane & 15, quad = lane >> 4;
    int m0 = blockIdx.x * 128, n0 = blockIdx.y * 128;

    f32x4 acc[4][4] = {};
    for (int k0 = 0; k0 < K; k0 += 32) {
        stage_tile4(A, K, m0, k0, smA, tid);
        stage_tile4(BT, K, n0, k0, smB, tid);
        __syncthreads();
        bf16x8 af[4], bfr[4];
#pragma unroll
        for (int mi = 0; mi < 4; ++mi)
            af[mi] = *(const bf16x8*)(smA + (wr * 64 + mi * 16 + m16) * 32 + quad * 8);
#pragma unroll
        for (int nj = 0; nj < 4; ++nj)
            bfr[nj] = *(const bf16x8*)(smB + (wc * 64 + nj * 16 + m16) * 32 + quad * 8);
#pragma unroll
        for (int mi = 0; mi < 4; ++mi)
#pragma unroll
            for (int nj = 0; nj < 4; ++nj)
                acc[mi][nj] = __builtin_amdgcn_mfma_f32_16x16x32_bf16(
                    af[mi], bfr[nj], acc[mi][nj], 0, 0, 0);
        __syncthreads();
    }
#pragma unroll
    for (int mi = 0; mi < 4; ++mi)
#pragma unroll
        for (int nj = 0; nj < 4; ++nj) {
            int mg = m0 + wr * 64 + mi * 16 + quad * 4;
            int ng = n0 + wc * 64 + nj * 16 + m16;
            float bv = bias[ng];
#pragma unroll
            for (int r = 0; r < 4; ++r) {
                float v = acc[mi][nj][r] + bv;
                v = v > 0.f ? v : 0.01f * v;
                C[(size_t)(mg + r) * N + ng] = f2bf(v);
            }
        }
}

// ------------- Chunk-parallel scan: 256 blocks x 512 threads ----------------
__global__ __launch_bounds__(512) void scan2_k(
    const unsigned short* __restrict__ bu, unsigned short* __restrict__ xs,
    const float* __restrict__ dones,
    const float* __restrict__ h0re, const float* __restrict__ h0im,
    const float* __restrict__ lamre, const float* __restrict__ lamim,
    const float* __restrict__ lstep,
    float* __restrict__ outre, float* __restrict__ outim)
{
    __shared__ float sdone[TT];
    __shared__ float4 ssum[8][64];
    __shared__ float2 shin[8][64];
    int tid = threadIdx.x;
    int b  = blockIdx.x >> 1;
    int ph = blockIdx.x & 1;
    int chunk = tid >> 6, pl = tid & 63;
    int p = ph * 64 + pl;
    sdone[tid] = dones[tid * BB + b];
    float lr = lamre[p], li = lamim[p];
    float st = expf(lstep[p]);
    float er = expf(lr * st);
    float ar = er * cosf(li * st);
    float ai = er * sinf(li * st);
    __syncthreads();

    int t0 = chunk * 64;
    unsigned buf[64];
    float Ar = 1.f, Ai = 0.f, br = 0.f, bi = 0.f;
#pragma unroll
    for (int j = 0; j < 64; ++j) {
        size_t base = ((size_t)(t0 + j) * BB + b) * 256;
        unsigned short rr = bu[base + p];
        unsigned short ii = bu[base + 128 + p];
        buf[j] = ((unsigned)ii << 16) | rr;
        float bur = bf2f(rr), bui = bf2f(ii);
        if (sdone[t0 + j] != 0.f) {
            Ar = 0.f; Ai = 0.f; br = bur; bi = bui;
        } else {
            float nAr = ar * Ar - ai * Ai;
            float nAi = ar * Ai + ai * Ar;
            float nbr = fmaf(ar, br, fmaf(-ai, bi, bur));
            float nbi = fmaf(ar, bi, fmaf(ai, br, bui));
            Ar = nAr; Ai = nAi; br = nbr; bi = nbi;
        }
    }
    ssum[chunk][pl] = float4{Ar, Ai, br, bi};
    __syncthreads();
    if (tid < 64) {
        int gid = b * 128 + p;
        float hr = h0re[gid], hi = h0im[gid];
#pragma unroll
        for (int c = 0; c < 8; ++c) {
            shin[c][pl] = float2{hr, hi};
            float4 s = ssum[c][pl];
            float nhr = fmaf(s.x, hr, fmaf(-s.y, hi, s.z));
            float nhi = fmaf(s.x, hi, fmaf(s.y, hr, s.w));
            hr = nhr; hi = nhi;
        }
        outre[gid] = hr; outim[gid] = hi;
    }
    __syncthreads();
    float hr = shin[chunk][pl].x, hi = shin[chunk][pl].y;
#pragma unroll
    for (int j = 0; j < 64; ++j) {
        unsigned v = buf[j];
        float bur = bf2f((unsigned short)(v & 0xFFFFu));
        float bui = bf2f((unsigned short)(v >> 16));
        float nr, ni;
        if (sdone[t0 + j] != 0.f) { nr = bur; ni = bui; }
        else {
            nr = fmaf(ar, hr, fmaf(-ai, hi, bur));
            ni = fmaf(ar, hi, fmaf(ai, hr, bui));
        }
        hr = nr; hi = ni;
        size_t base = ((size_t)(t0 + j) * BB + b) * 256;
        xs[base + p] = f2bf(nr);
        xs[base + 128 + p] = f2bf(ni);
    }
}

// -------- Precompute B_barT [n=2P][k=H] and CcatT [n=H][k=2P] in bf16 --------
__global__ __launch_bounds__(256) void prep_k(
    const float* __restrict__ Br, const float* __restrict__ Bi,
    const float* __restrict__ Cr, const float* __restrict__ Ci,
    const float* __restrict__ Lr, const float* __restrict__ Li,
    const float* __restrict__ ls, unsigned short* bbarT, unsigned short* ccatT)
{
    int gid = blockIdx.x * 256 + threadIdx.x;   // L*P*H = 131072
    int l = gid >> 15;
    int rem = gid & 32767;
    int p = rem >> 8;
    int h = rem & 255;
    float lr = Lr[l * PD + p], li = Li[l * PD + p];
    float st = expf(ls[l * PD + p]);
    float er = expf(lr * st);
    float lbr = er * cosf(li * st);
    float lbi = er * sinf(li * st);
    float nr = lbr - 1.f, ni = lbi;
    float den = lr * lr + li * li;
    float fr = (nr * lr + ni * li) / den;
    float fi = (ni * lr - nr * li) / den;
    float bre = Br[(size_t)(l * PD + p) * HD + h];
    float bim = Bi[(size_t)(l * PD + p) * HD + h];
    size_t lb = (size_t)l * 65536;
    bbarT[lb + (size_t)p * 256 + h]         = f2bf(fr * bre - fi * bim);
    bbarT[lb + (size_t)(128 + p) * 256 + h] = f2bf(fr * bim + fi * bre);
    float cre = Cr[(size_t)(l * HD + h) * PD + p];
    float cim = Ci[(size_t)(l * HD + h) * PD + p];
    ccatT[lb + (size_t)h * 256 + p]         = f2bf(2.f * cre);
    ccatT[lb + (size_t)h * 256 + 128 + p]   = f2bf(-2.f * cim);
}

// -------- transpose+convert: in f32 [K][N] -> out bf16 [N][K] ---------------
__global__ __launch_bounds__(256) void tcvt_k(const float* __restrict__ in,
    unsigned short* __restrict__ out, int K, int N)
{
    int gid = blockIdx.x * 256 + threadIdx.x;
    if (gid >= K * N) return;
    int k = gid / N, n = gid - k * N;
    out[(size_t)n * K + k] = f2bf(in[gid]);
}

// -------- straight convert f32 -> bf16, 4 elements / thread -----------------
__global__ __launch_bounds__(256) void cvt_k(const float* __restrict__ in,
    unsigned short* __restrict__ out)
{
    size_t gid = (size_t)blockIdx.x * 256 + threadIdx.x;
    float4 v = ((const float4*)in)[gid];
    ushort4 o = { f2bf(v.x), f2bf(v.y), f2bf(v.z), f2bf(v.w) };
    ((ushort4*)out)[gid] = o;
}

// ---------------- Final heads: wave per row -> out[row*9 + ...] -------------
__global__ __launch_bounds__(256) void head_k(
    const unsigned short* __restrict__ am2, const unsigned short* __restrict__ v2,
    const float* __restrict__ adW, const float* __restrict__ adb,
    const float* __restrict__ lstd,
    const float* __restrict__ vdW, const float* __restrict__ vdb,
    float* out)
{
    int wid = threadIdx.x >> 6, lane = threadIdx.x & 63;
    size_t row = (size_t)blockIdx.x * 4 + wid;
    float a1 = bf2f(am2[row * 128 + lane]);
    float a2 = bf2f(am2[row * 128 + 64 + lane]);
    float w1 = bf2f(v2[row * 128 + lane]);
    float w2 = bf2f(v2[row * 128 + 64 + lane]);
    float vals[5];
#pragma unroll
    for (int a = 0; a < 4; ++a)
        vals[a] = a1 * adW[lane * 4 + a] + a2 * adW[(lane + 64) * 4 + a];
    vals[4] = w1 * vdW[lane] + w2 * vdW[64 + lane];
#pragma unroll
    for (int off = 32; off; off >>= 1)
#pragma unroll
        for (int k = 0; k < 5; ++k) vals[k] += __shfl_xor(vals[k], off);
    if (lane == 0) {
        size_t o = row * 9;
#pragma unroll
        for (int a = 0; a < 4; ++a) out[o + a] = vals[a] + adb[a];
#pragma unroll
        for (int a = 0; a < 4; ++a) out[o + 4 + a] = expf(lstd[a]);
        out[o + 8] = vals[4] + vdb[0];
    }
}

extern "C" void kernel_launch(void* const* d_in, const int* in_sizes, int n_in,
                              void* d_out, int out_size, void* d_ws, size_t ws_size,
                              hipStream_t stream) {
    (void)in_sizes; (void)n_in; (void)out_size; (void)ws_size;
    const float* obs     = (const float*)d_in[0];
    const float* dones   = (const float*)d_in[1];
    const float* hre     = (const float*)d_in[2];
    const float* him     = (const float*)d_in[3];
    const float* enc0_W  = (const float*)d_in[4];
    const float* enc0_b  = (const float*)d_in[5];
    const float* enc1_W  = (const float*)d_in[6];
    const float* enc1_b  = (const float*)d_in[7];
    const float* nsc     = (const float*)d_in[8];
    const float* nbi     = (const float*)d_in[9];
    const float* Lre     = (const float*)d_in[10];
    const float* Lim     = (const float*)d_in[11];
    const float* B_re    = (const float*)d_in[12];
    const float* B_im    = (const float*)d_in[13];
    const float* C_re    = (const float*)d_in[14];
    const float* C_im    = (const float*)d_in[15];
    const float* Dv      = (const float*)d_in[16];
    const float* lstep   = (const float*)d_in[17];
    const float* glu_W   = (const float*)d_in[18];
    const float* glu_b   = (const float*)d_in[19];
    const float* ab0_W   = (const float*)d_in[20];
    const float* ab0_b   = (const float*)d_in[21];
    const float* ab1_W   = (const float*)d_in[22];
    const float* ab1_b   = (const float*)d_in[23];
    const float* adec_W  = (const float*)d_in[24];
    const float* adec_b  = (const float*)d_in[25];
    const float* log_std = (const float*)d_in[26];
    const float* vb0_W   = (const float*)d_in[27];
    const float* vb0_b   = (const float*)d_in[28];
    const float* vb1_W   = (const float*)d_in[29];
    const float* vb1_b   = (const float*)d_in[30];
    const float* vdec_W  = (const float*)d_in[31];
    const float* vdec_b  = (const float*)d_in[32];

    const size_t MB = (size_t)1 << 20;
    char* wsb = (char*)d_ws;
    unsigned short* OBSBF = (unsigned short*)(wsb);              // 64MB (enc0 only)
    unsigned short* XS    = (unsigned short*)(wsb);              // 32MB (per-layer xs)
    unsigned short* AM1   = (unsigned short*)(wsb);              // 16MB (heads)
    unsigned short* V1    = (unsigned short*)(wsb + 16 * MB);    // 16MB (heads)
    unsigned short* AM2   = (unsigned short*)(wsb + 32 * MB);    // 16MB (heads)
    unsigned short* V2    = (unsigned short*)(wsb + 48 * MB);    // 16MB (heads)
    unsigned short* U1    = (unsigned short*)(wsb + 64 * MB);    // 16MB (enc0 out)
    unsigned short* X     = (unsigned short*)(wsb + 96 * MB);    // 32MB residual bf16
    unsigned short* U     = (unsigned short*)(wsb + 128 * MB);   // 32MB (u / z)
    unsigned short* BU    = (unsigned short*)(wsb + 160 * MB);   // 32MB (Bu)
    char* wgt = wsb + 192 * MB;
    unsigned short* BBART = (unsigned short*)(wgt);              // 512KB
    unsigned short* CCATT = (unsigned short*)(wgt + 512 * 1024);
    unsigned short* GLUT  = (unsigned short*)(wgt + 1024 * 1024);
    unsigned short* E0T   = (unsigned short*)(wgt + 1536 * 1024);
    unsigned short* E1T   = (unsigned short*)(wgt + 1664 * 1024);
    unsigned short* AB0T  = (unsigned short*)(wgt + 1728 * 1024);
    unsigned short* AB1T  = (unsigned short*)(wgt + 1792 * 1024);
    unsigned short* VB0T  = (unsigned short*)(wgt + 1824 * 1024);
    unsigned short* VB1T  = (unsigned short*)(wgt + 1888 * 1024);

    float* out   = (float*)d_out;
    float* outre = out + (size_t)NTB * 9;
    float* outim = outre + LD * BB * PD;

    // ---- weight prep ----
    prep_k<<<512, 256, 0, stream>>>(B_re, B_im, C_re, C_im, Lre, Lim, lstep, BBART, CCATT);
    tcvt_k<<<256, 256, 0, stream>>>(enc0_W, E0T, 512, 128);
    tcvt_k<<<128, 256, 0, stream>>>(enc1_W, E1T, 128, 256);
    for (int l = 0; l < LD; ++l)
        tcvt_k<<<256, 256, 0, stream>>>(glu_W + (size_t)l * 65536, GLUT + (size_t)l * 65536, 256, 256);
    tcvt_k<<<128, 256, 0, stream>>>(ab0_W, AB0T, 256, 128);
    tcvt_k<<<64, 256, 0, stream>>>(ab1_W, AB1T, 128, 128);
    tcvt_k<<<128, 256, 0, stream>>>(vb0_W, VB0T, 256, 128);
    tcvt_k<<<64, 256, 0, stream>>>(vb1_W, VB1T, 128, 128);
    cvt_k<<<32768, 256, 0, stream>>>(obs, OBSBF);

    // ---- encoder ----
    mgemm<<<dim3(512, 1), 256, 0, stream>>>(OBSBF, E0T, U1, NTB, 128, 512, enc0_b);
    // enc1 fused: X = leaky(U1@E1+b), U = LN_0(X)
    mgemm2<0><<<512, 512, 0, stream>>>(U1, E1T, 128, enc1_b, nsc, nbi, nullptr, X, U, 1);

    // ---- S5 layers ----
    for (int l = 0; l < LD; ++l) {
        mgemm2<1><<<512, 512, 0, stream>>>(U, BBART + (size_t)l * 65536, 256,
                                           nullptr, nullptr, nullptr, nullptr, nullptr, BU, 0);
        scan2_k<<<256, 512, 0, stream>>>(BU, XS, dones, hre + l * BB * PD, him + l * BB * PD,
                                         Lre + l * PD, Lim + l * PD, lstep + l * PD,
                                         outre + l * BB * PD, outim + l * BB * PD);
        // z = gelu(LN_l(xs@C + D*u))   (in-place U: aux1=U read, U written)
        mgemm2<2><<<512, 512, 0, stream>>>(XS, CCATT + (size_t)l * 65536, 256,
                                           Dv + l * HD, nsc + l * HD, nbi + l * HD, U, nullptr, U, 1);
        // x += z*sigmoid(z@W+b); u_next = LN_{l+1}(x)  (skip LN on last layer)
        const float* nsc2 = nsc + ((l + 1 < LD) ? (l + 1) * HD : 0);
        const float* nbi2 = nbi + ((l + 1 < LD) ? (l + 1) * HD : 0);
        mgemm2<3><<<512, 512, 0, stream>>>(U, GLUT + (size_t)l * 65536, 256,
                                           glu_b + l * HD, nsc2, nbi2, U, X, U, (l + 1 < LD) ? 1 : 0);
    }

    // ---- heads ----
    mgemm<<<dim3(512, 1), 256, 0, stream>>>(X, AB0T, AM1, NTB, 128, 256, ab0_b);
    mgemm<<<dim3(512, 1), 256, 0, stream>>>(AM1, AB1T, AM2, NTB, 128, 128, ab1_b);
    mgemm<<<dim3(512, 1), 256, 0, stream>>>(X, VB0T, V1, NTB, 128, 256, vb0_b);
    mgemm<<<dim3(512, 1), 256, 0, stream>>>(V1, VB1T, V2, NTB, 128, 128, vb1_b);
    head_k<<<NTB / 4, 256, 0, stream>>>(AM2, V2, adec_W, adec_b, log_std, vdec_W, vdec_b, out);
}